// Round 4
// baseline (33.250 us; speedup 1.0000x reference)
//
#include <hip/hip_runtime.h>

// query:          [N=8, C=640, H=48, W=48] f32
// dynamic_filter: [N=8, 2304, 9, 1] f32   (per-pixel 3x3 taps, shared over C)
// out1 = relu(dynamic 3x3 conv): [8,640,48,48] f32
// out2 = zeros_like(dynamic_filter)
//
// Structure: 1 thread = 1 aligned float4 strip (h, w0..w0+3) x CH channels.
// All boundary handling is folded into the per-pixel taps (zero the tap,
// not the input), so the channel loop has ZERO branches/selects:
// 9 unconditional loads + 36 FMA + 1 store, with a 2-deep register
// prefetch across channels for MLP.
#define N_   8
#define C_   640
#define H_   48
#define W_   48
#define K_   9
#define CH   5
#define NCC  (C_ / CH)          // 128 channel chunks
#define BLK  256
#define OUT1_ELEMS ((size_t)N_ * C_ * H_ * W_)   // 11,796,480
#define OUT2_ELEMS ((size_t)N_ * H_ * W_ * K_)   //    165,888

typedef float f4 __attribute__((ext_vector_type(4)));

__global__ __launch_bounds__(BLK) void dynconv(
    const float* __restrict__ q,
    const float* __restrict__ df,
    float* __restrict__ out)
{
    const int g  = blockIdx.x * BLK + threadIdx.x;   // exact: 2304*256 = 8*128*576
    const int w4 = g % 12;
    const int h  = (g / 12) % H_;
    const int cc = (g / (12 * H_)) % NCC;
    const int n  = g / (12 * H_ * NCC);
    const int w0 = w4 * 4;
    const int c0 = cc * CH;

    // ---- zero out2 (folded in; no separate memset dispatch) ----
    if (g < (int)OUT2_ELEMS) out[OUT1_ELEMS + g] = 0.f;

    // ---- per-pixel taps: 36 contiguous floats, 144B-aligned -> 9 f4 loads.
    //      layout: f[p*9 + dy*3 + dx] for pixel p of the strip ----
    float f[36];
    {
        const f4* dfp = (const f4*)(df + (size_t)(n * (H_ * W_) + h * W_ + w0) * K_);
#pragma unroll
        for (int i = 0; i < 9; ++i) {
            f4 v = dfp[i];
            f[4*i+0] = v.x; f[4*i+1] = v.y; f[4*i+2] = v.z; f[4*i+3] = v.w;
        }
    }
    // ---- fold ALL boundary zeroing into taps (input addrs get clamped) ----
    if (h == 0) {
#pragma unroll
        for (int p = 0; p < 4; ++p) { f[p*9+0]=0.f; f[p*9+1]=0.f; f[p*9+2]=0.f; }
    }
    if (h == H_ - 1) {
#pragma unroll
        for (int p = 0; p < 4; ++p) { f[p*9+6]=0.f; f[p*9+7]=0.f; f[p*9+8]=0.f; }
    }
    if (w4 == 0)  { f[0]  = 0.f; f[3]  = 0.f; f[6]  = 0.f; }  // pixel0 left col
    if (w4 == 11) { f[29] = 0.f; f[32] = 0.f; f[35] = 0.f; }  // pixel3 right col

    // ---- clamped, always-valid offsets (relative to this strip's base) ----
    int roff[3], loff[3], goff[3];
#pragma unroll
    for (int dy = 0; dy < 3; ++dy) {
        int r  = h + dy - 1;
        int rc = min(max(r, 0), H_ - 1);
        roff[dy] = (rc - h) * W_;
        loff[dy] = roff[dy] + ((w4 > 0)  ? -1 : 0);
        goff[dy] = roff[dy] + ((w4 < 11) ?  4 : 3);
    }

    const size_t plane = (size_t)H_ * W_;
    const float* qbase = q   + ((size_t)(n * C_ + c0)) * plane + h * W_ + w0;
    float*       obase = out + ((size_t)(n * C_ + c0)) * plane + h * W_ + w0;

    // ---- prologue: load channel 0 ----
    f4 m0[3]; float l0[3], r0[3];
#pragma unroll
    for (int dy = 0; dy < 3; ++dy) {
        m0[dy] = *(const f4*)(qbase + roff[dy]);
        l0[dy] = qbase[loff[dy]];
        r0[dy] = qbase[goff[dy]];
    }

#pragma unroll
    for (int ci = 0; ci < CH; ++ci) {
        // prefetch next channel (9 unconditional loads in flight)
        f4 m1[3]; float l1[3], r1[3];
        if (ci + 1 < CH) {
            const float* qp = qbase + (size_t)(ci + 1) * plane;
#pragma unroll
            for (int dy = 0; dy < 3; ++dy) {
                m1[dy] = *(const f4*)(qp + roff[dy]);
                l1[dy] = qp[loff[dy]];
                r1[dy] = qp[goff[dy]];
            }
        }

        // compute current channel: 36 FMAs, no masking needed
        f4 acc = (f4){0.f, 0.f, 0.f, 0.f};
#pragma unroll
        for (int dy = 0; dy < 3; ++dy) {
            const int fb = dy * 3;
            acc.x = fmaf(f[ 0 + fb], l0[dy],   acc.x);
            acc.x = fmaf(f[ 1 + fb], m0[dy].x, acc.x);
            acc.x = fmaf(f[ 2 + fb], m0[dy].y, acc.x);

            acc.y = fmaf(f[ 9 + fb], m0[dy].x, acc.y);
            acc.y = fmaf(f[10 + fb], m0[dy].y, acc.y);
            acc.y = fmaf(f[11 + fb], m0[dy].z, acc.y);

            acc.z = fmaf(f[18 + fb], m0[dy].y, acc.z);
            acc.z = fmaf(f[19 + fb], m0[dy].z, acc.z);
            acc.z = fmaf(f[20 + fb], m0[dy].w, acc.z);

            acc.w = fmaf(f[27 + fb], m0[dy].z, acc.w);
            acc.w = fmaf(f[28 + fb], m0[dy].w, acc.w);
            acc.w = fmaf(f[29 + fb], r0[dy],   acc.w);
        }

        acc.x = fmaxf(acc.x, 0.f);
        acc.y = fmaxf(acc.y, 0.f);
        acc.z = fmaxf(acc.z, 0.f);
        acc.w = fmaxf(acc.w, 0.f);
        *(f4*)(obase + (size_t)ci * plane) = acc;

        // rotate prefetched regs (full unroll -> pure SSA renaming)
        if (ci + 1 < CH) {
#pragma unroll
            for (int dy = 0; dy < 3; ++dy) {
                m0[dy] = m1[dy]; l0[dy] = l1[dy]; r0[dy] = r1[dy];
            }
        }
    }
}

extern "C" void kernel_launch(void* const* d_in, const int* in_sizes, int n_in,
                              void* d_out, int out_size, void* d_ws, size_t ws_size,
                              hipStream_t stream)
{
    const float* q  = (const float*)d_in[0];
    const float* df = (const float*)d_in[1];
    float* out = (float*)d_out;

    const int total_threads = N_ * NCC * H_ * 12;        // 589,824
    const int blocks = total_threads / BLK;              // 2304
    dynconv<<<blocks, BLK, 0, stream>>>(q, df, out);
}